// Round 4
// baseline (550.753 us; speedup 1.0000x reference)
//
#include <hip/hip_runtime.h>
#include <hip/hip_bf16.h>

typedef float  f32x4  __attribute__((ext_vector_type(4)));
typedef short  bf16x8 __attribute__((ext_vector_type(8)));
typedef short  bf16x4 __attribute__((ext_vector_type(4)));

typedef const void __attribute__((address_space(1))) gv_t;
typedef void __attribute__((address_space(3))) sv_t;

namespace {

constexpr int B_ = 2;
constexpr int S_ = 1024;
constexpr int H_ = 1024;
constexpr int V_ = 50257;
constexpr int M_ = B_ * S_;          // 2048
constexpr int VP2_ = 50432;          // 197*256, zero-padded W_lm rows (fast path)
constexpr int VP1_ = 50304;          // 393*128 (mid path)
constexpr float DT_ = 0.1f;
constexpr float THRESH_ = 10.0f;

constexpr int BK = 64;
constexpr int NT = H_ / BK;          // 16 K-tiles

__device__ __forceinline__ unsigned short f2bf(float f) {
  union { float f; unsigned u; } x;
  x.f = f;
  x.u += 0x7FFFu + ((x.u >> 16) & 1u);   // RNE (no NaNs in this problem)
  return (unsigned short)(x.u >> 16);
}

// ---------------- Kernel 1: hidden f32 -> bf16, fused with impulse dot
__global__ void cvt_hidden_impulse_kernel(const float* __restrict__ hidden,
                                          const float* __restrict__ W_imp,
                                          const float* __restrict__ b_imp,
                                          unsigned short* __restrict__ hid_bf,
                                          float* __restrict__ imp) {
  const int m = blockIdx.x;
  const int t = threadIdx.x;
  const float4 hv = reinterpret_cast<const float4*>(hidden + (size_t)m * H_)[t];
  const float4 wv = reinterpret_cast<const float4*>(W_imp)[t];   // row 0
  bf16x4 o;
  o[0] = (short)f2bf(hv.x); o[1] = (short)f2bf(hv.y);
  o[2] = (short)f2bf(hv.z); o[3] = (short)f2bf(hv.w);
  *(bf16x4*)(hid_bf + (size_t)m * H_ + t * 4) = o;
  float p = hv.x * wv.x + hv.y * wv.y + hv.z * wv.z + hv.w * wv.w;
  #pragma unroll
  for (int off = 32; off; off >>= 1) p += __shfl_down(p, off);
  __shared__ float partial[4];
  if ((t & 63) == 0) partial[t >> 6] = p;
  __syncthreads();
  if (t == 0) {
    const float v = partial[0] + partial[1] + partial[2] + partial[3] + b_imp[0];
    const int b = m >> 10;
    const int s = m & (S_ - 1);
    imp[s * B_ + b] = v;
  }
}

// ---------------- scan body (device fn; used standalone and fused)
__device__ __forceinline__ void scan_body(const float* __restrict__ imp_s,
                                          const float* __restrict__ ttu_state,
                                          const float* __restrict__ ttu_params,
                                          float* __restrict__ states,
                                          float* __restrict__ final_out, int t) {
  if (t < B_) {
    const float gamma   = ttu_params[0];
    const float alpha_c = ttu_params[1];
    const float beta_c  = ttu_params[2];
    const float delta   = ttu_params[3];
    const float alpha_d = ttu_params[4];
    const float epsilon = ttu_params[5];
    const float alpha_m = ttu_params[6];
    float c = ttu_state[t * 3 + 0];
    float d = ttu_state[t * 3 + 1];
    float m = ttu_state[t * 3 + 2];
    for (int s = 0; s < S_; ++s) {
      const float ii = imp_s[s * B_ + t];
      const float dc = gamma * ii - alpha_c * c - beta_c * c * d;
      const float dd = delta * c * c - alpha_d * d;
      const float dm = epsilon * d - alpha_m * m;
      c = c + DT_ * dc;
      float nd = d + DT_ * dd;
      m = m + DT_ * dm;
      nd = (fabsf(nd) > THRESH_ ? 0.5f : 1.0f) * nd;
      d = nd;
      float* st = states + (size_t)(s * B_ + t) * 3;
      st[0] = c; st[1] = d; st[2] = m;
    }
    final_out[t * 3 + 0] = c;
    final_out[t * 3 + 1] = d;
    final_out[t * 3 + 2] = m;
  }
}

// ---------------- Kernel 2 (standalone scan, fallback paths)
__global__ void ttu_scan_kernel(const float* __restrict__ imp,
                                const float* __restrict__ ttu_state,
                                const float* __restrict__ ttu_params,
                                float* __restrict__ states,
                                float* __restrict__ final_out) {
  __shared__ float imp_s[S_ * B_];
  const int t = threadIdx.x;  // 64
  for (int i = t; i < S_ * B_; i += 64) imp_s[i] = imp[i];
  __syncthreads();
  scan_body(imp_s, ttu_state, ttu_params, states, final_out, t);
}

// ---------------- Kernel 2.5: W_lm f32 -> bf16 (zero-fill pad rows), scan fused
// last block (blockIdx == gridDim-1) runs the serial scan instead (hides its
// ~12us under the ~50us convert). Other blocks stride over the convert.
__global__ void cvt_wlm_scan_kernel(const float* __restrict__ src,
                                    unsigned short* __restrict__ dst,
                                    long n_src, long n_dst,
                                    const float* __restrict__ imp,
                                    const float* __restrict__ ttu_state,
                                    const float* __restrict__ ttu_params,
                                    float* __restrict__ states,
                                    float* __restrict__ final_out) {
  __shared__ float imp_s[S_ * B_];
  const int t = threadIdx.x;   // 256
  if (blockIdx.x == gridDim.x - 1) {
    for (int i = t; i < S_ * B_; i += 256) imp_s[i] = imp[i];
    __syncthreads();
    scan_body(imp_s, ttu_state, ttu_params, states, final_out, t);
    return;
  }
  const long stride = (long)(gridDim.x - 1) * blockDim.x * 8;
  for (long i = ((long)blockIdx.x * blockDim.x + t) * 8; i < n_dst; i += stride) {
    bf16x8 v;
    if (i < n_src) {     // n_src multiple of 8; vectors never straddle
      const float4 a = *(const float4*)(src + i);
      const float4 b = *(const float4*)(src + i + 4);
      v[0] = (short)f2bf(a.x); v[1] = (short)f2bf(a.y);
      v[2] = (short)f2bf(a.z); v[3] = (short)f2bf(a.w);
      v[4] = (short)f2bf(b.x); v[5] = (short)f2bf(b.y);
      v[6] = (short)f2bf(b.z); v[7] = (short)f2bf(b.w);
    } else {
      v = (bf16x8){0, 0, 0, 0, 0, 0, 0, 0};
    }
    *(bf16x8*)(dst + i) = v;
  }
}

__global__ void cvt_bf16_kernel(const float* __restrict__ src,
                                unsigned short* __restrict__ dst,
                                long n_src, long n_dst) {
  const long stride = (long)gridDim.x * blockDim.x * 8;
  for (long i = ((long)blockIdx.x * blockDim.x + threadIdx.x) * 8; i < n_dst; i += stride) {
    bf16x8 v;
    if (i < n_src) {
      const float4 a = *(const float4*)(src + i);
      const float4 b = *(const float4*)(src + i + 4);
      v[0] = (short)f2bf(a.x); v[1] = (short)f2bf(a.y);
      v[2] = (short)f2bf(a.z); v[3] = (short)f2bf(a.w);
      v[4] = (short)f2bf(b.x); v[5] = (short)f2bf(b.y);
      v[6] = (short)f2bf(b.z); v[7] = (short)f2bf(b.w);
    } else {
      v = (bf16x8){0, 0, 0, 0, 0, 0, 0, 0};
    }
    *(bf16x8*)(dst + i) = v;
  }
}

// ---------------- Kernel 3 (fast): 256x256 tile, 4-phase/K-tile, counted vmcnt
// Schedule derivation (race-free ledger):
//  - double LDS buffers; tile kt in buf[kt&1]; during kt stage kt+1 into the
//    other buf, one 16KB half-tile (2 gload_lds x16B/thread) per phase.
//  - p0: stage half0 -> s_waitcnt vmcnt(2) (the 2 just-issued are the ONLY
//    loads allowed outstanding => previous tile's 8 loads complete) ->
//    s_barrier (publish all waves' stages). RAW safe.
//  - end-of-tile s_barrier: every wave's ds_reads of cur drained by its p3
//    lgkmcnt(0) before arriving => next tile's stage writes are WAR safe.
//  - NO __syncthreads in the loop (it would drain vmcnt(0)).
__global__ __launch_bounds__(512, 2) void ttu_gemm_bf16_256_kernel(
    const unsigned short* __restrict__ Ab,   // hidden bf16 [M_][H_]
    const unsigned short* __restrict__ Bb,   // W_lm bf16 [VP2_][H_]
    const float* __restrict__ states,
    const float* __restrict__ Wmod,
    float* __restrict__ out)
{
  __shared__ unsigned short A_s[2][256 * BK];   // 64 KiB
  __shared__ unsigned short B_s[2][256 * BK];   // 64 KiB
  __shared__ float st_s[256][3];
  __shared__ float wm_s[256][3];

  const int t = threadIdx.x;
  const int cpx = gridDim.x >> 3;              // 197; grid 1576 % 8 == 0
  const int bid = (blockIdx.x & 7) * cpx + (blockIdx.x >> 3);
  const int mb = bid & 7;                      // M fastest: share B-panel
  const int nb = bid >> 3;
  const int m0 = mb * 256;
  const int n0 = nb * 256;

  if (t < 256) {
    const int m = m0 + t;
    const int b = m >> 10;
    const int s = m & (S_ - 1);
    const float* st = states + (size_t)(s * B_ + b) * 3;
    st_s[t][0] = st[0]; st_s[t][1] = st[1]; st_s[t][2] = st[2];
  } else {
    const int tt = t - 256;
    const int n = n0 + tt;
    const bool ok = n < V_;
    wm_s[tt][0] = ok ? Wmod[n * 3 + 0] : 0.f;
    wm_s[tt][1] = ok ? Wmod[n * 3 + 1] : 0.f;
    wm_s[tt][2] = ok ? Wmod[n * 3 + 2] : 0.f;
  }

  const int lane = t & 63;
  const int wid  = t >> 6;             // 8 waves
  const int lr   = lane >> 3;          // staging sub-row 0..7
  const int ch   = lane & 7;           // staging 16B chunk 0..7
  const int wmi  = wid >> 2;           // wave row 0..1 (128 rows each)
  const int wni  = wid & 3;            // wave col 0..3 (64 cols each)
  const int lm   = lane & 15;
  const int kg   = lane >> 4;

  const unsigned short* Abase = Ab + (size_t)m0 * H_;
  const unsigned short* Bbase = Bb + (size_t)n0 * H_;

  // stage half h (0:A rows0-127, 1:A rows128-255, 2:B0, 3:B1) of tile kt
  // LDS dest = wave-uniform base + lane*16B (rule #21: linear dest,
  // inverse-swizzled SOURCE chunk; ds_read applies the same XOR).
  auto STAGE_HALF = [&](int buf, int kt, int h) {
    const int k0 = kt * BK;
    const unsigned short* gb = (h < 2) ? Abase : Bbase;
    unsigned short* ls = (h < 2) ? &A_s[buf][0] : &B_s[buf][0];
    const int half = (h & 1) * 128;
    #pragma unroll
    for (int n = 0; n < 2; ++n) {
      const int rbase = half + wid * 16 + n * 8;   // wave-uniform
      const int r  = rbase + lr;
      const int sc = ch ^ (r & 7);
      __builtin_amdgcn_global_load_lds(
          (gv_t*)(gb + (size_t)r * H_ + k0 + sc * 8),
          (sv_t*)(ls + rbase * BK), 16, 0, 0);
    }
  };

  f32x4 acc[8][4];
  #pragma unroll
  for (int i = 0; i < 8; ++i)
    #pragma unroll
    for (int j = 0; j < 4; ++j)
      acc[i][j] = (f32x4){0.f, 0.f, 0.f, 0.f};

  // prologue: tile 0 -> buf0, full drain once
  #pragma unroll
  for (int h = 0; h < 4; ++h) STAGE_HALF(0, 0, h);
  asm volatile("s_waitcnt vmcnt(0)" ::: "memory");
  __builtin_amdgcn_s_barrier();
  __builtin_amdgcn_sched_barrier(0);

  int cur = 0;
  bf16x8 bfr[4][2];

  for (int kt = 0; kt < NT; ++kt) {
    const int nxt = cur ^ 1;
    const bool more = (kt + 1 < NT);
    const unsigned short* As = &A_s[cur][0];
    const unsigned short* Bs = &B_s[cur][0];

    // ---- phase 0 head: stage half0, counted wait, publish barrier
    if (more) {
      STAGE_HALF(nxt, kt + 1, 0);
      asm volatile("s_waitcnt vmcnt(2)" ::: "memory");
    } else {
      asm volatile("s_waitcnt vmcnt(0)" ::: "memory");
    }
    __builtin_amdgcn_s_barrier();
    __builtin_amdgcn_sched_barrier(0);

    #pragma unroll
    for (int q = 0; q < 4; ++q) {
      if (q > 0 && more) STAGE_HALF(nxt, kt + 1, q);
      if (q == 0) {
        #pragma unroll
        for (int j = 0; j < 4; ++j)
          #pragma unroll
          for (int ks = 0; ks < 2; ++ks) {
            const int r = wni * 64 + j * 16 + lm;
            bfr[j][ks] = *(const bf16x8*)&Bs[r * BK + (((ks * 4 + kg) ^ (r & 7)) << 3)];
          }
      }
      bf16x8 af[2][2];
      #pragma unroll
      for (int i2 = 0; i2 < 2; ++i2)
        #pragma unroll
        for (int ks = 0; ks < 2; ++ks) {
          const int r = wmi * 128 + (q * 2 + i2) * 16 + lm;
          af[i2][ks] = *(const bf16x8*)&As[r * BK + (((ks * 4 + kg) ^ (r & 7)) << 3)];
        }
      asm volatile("s_waitcnt lgkmcnt(0)" ::: "memory");
      __builtin_amdgcn_sched_barrier(0);          // rule #18
      __builtin_amdgcn_s_setprio(1);
      #pragma unroll
      for (int ks = 0; ks < 2; ++ks)
        #pragma unroll
        for (int i2 = 0; i2 < 2; ++i2)
          #pragma unroll
          for (int j = 0; j < 4; ++j)
            acc[q * 2 + i2][j] = __builtin_amdgcn_mfma_f32_16x16x32_bf16(
                af[i2][ks], bfr[j][ks], acc[q * 2 + i2][j], 0, 0, 0);
      __builtin_amdgcn_s_setprio(0);
    }

    __builtin_amdgcn_s_barrier();   // end-of-tile: all reads of cur done
    __builtin_amdgcn_sched_barrier(0);
    cur ^= 1;
  }

  // Epilogue: += 0.1 * states . W_mod^T; row-major store order
  #pragma unroll
  for (int i = 0; i < 8; ++i) {
    #pragma unroll
    for (int rr = 0; rr < 4; ++rr) {
      const int mloc = wmi * 128 + i * 16 + kg * 4 + rr;
      const float s0 = st_s[mloc][0], s1 = st_s[mloc][1], s2 = st_s[mloc][2];
      float* orow = out + (size_t)(m0 + mloc) * V_ + n0;
      #pragma unroll
      for (int j = 0; j < 4; ++j) {
        const int nloc = wni * 64 + j * 16 + lm;
        if (n0 + nloc < V_) {
          const float corr = 0.1f * (s0 * wm_s[nloc][0] + s1 * wm_s[nloc][1] + s2 * wm_s[nloc][2]);
          orow[nloc] = acc[i][j][rr] + corr;
        }
      }
    }
  }
}

// ---------------- Kernel 3 (mid fallback): R3 128x128 2-phase double-buffer
__global__ __launch_bounds__(256) void ttu_gemm_bf16_db_kernel(
    const unsigned short* __restrict__ Ab,
    const unsigned short* __restrict__ Bb,   // [VP1_][H_]
    const float* __restrict__ states,
    const float* __restrict__ Wmod,
    float* __restrict__ out)
{
  __shared__ unsigned short AB_s[2][2][128 * BK];
  __shared__ float st_s[128][3];
  __shared__ float wm_s[128][3];

  const int t = threadIdx.x;
  const int cpx = gridDim.x >> 3;
  const int bid = (blockIdx.x & 7) * cpx + (blockIdx.x >> 3);
  const int mb = bid & 15;
  const int nb = bid >> 4;
  const int m0 = mb * 128;
  const int n0 = nb * 128;

  if (t < 128) {
    const int m = m0 + t;
    const int b = m >> 10;
    const int s = m & (S_ - 1);
    const float* st = states + (size_t)(s * B_ + b) * 3;
    st_s[t][0] = st[0]; st_s[t][1] = st[1]; st_s[t][2] = st[2];
  } else {
    const int tt = t - 128;
    const int n = n0 + tt;
    const bool ok = n < V_;
    wm_s[tt][0] = ok ? Wmod[n * 3 + 0] : 0.f;
    wm_s[tt][1] = ok ? Wmod[n * 3 + 1] : 0.f;
    wm_s[tt][2] = ok ? Wmod[n * 3 + 2] : 0.f;
  }

  const int lane = t & 63;
  const int wid  = t >> 6;
  const int lr   = lane >> 3;
  const int ch   = lane & 7;
  const int wm   = wid >> 1;
  const int wn   = wid & 1;
  const int lm   = lane & 15;
  const int kg   = lane >> 4;

  const unsigned short* Abase = Ab + (size_t)m0 * H_;
  const unsigned short* Bbase = Bb + (size_t)n0 * H_;
  const int r0 = wid * 32;

  auto STAGE = [&](unsigned short* As, unsigned short* Bs, int kt) {
    const int k0 = kt * BK;
    #pragma unroll
    for (int ins = 0; ins < 4; ++ins) {
      const int lrow = r0 + ins * 8 + lr;
      const int sch  = ch ^ (lrow & 7);
      __builtin_amdgcn_global_load_lds(
          (gv_t*)(Abase + (size_t)lrow * H_ + k0 + sch * 8),
          (sv_t*)(As + (r0 + ins * 8) * BK), 16, 0, 0);
    }
    #pragma unroll
    for (int ins = 0; ins < 4; ++ins) {
      const int lrow = r0 + ins * 8 + lr;
      const int sch  = ch ^ (lrow & 7);
      __builtin_amdgcn_global_load_lds(
          (gv_t*)(Bbase + (size_t)lrow * H_ + k0 + sch * 8),
          (sv_t*)(Bs + (r0 + ins * 8) * BK), 16, 0, 0);
    }
  };

  f32x4 acc[4][4];
  #pragma unroll
  for (int i = 0; i < 4; ++i)
    #pragma unroll
    for (int j = 0; j < 4; ++j)
      acc[i][j] = (f32x4){0.f, 0.f, 0.f, 0.f};

  unsigned short* Ac = &AB_s[0][0][0];
  unsigned short* Bc = &AB_s[0][1][0];
  unsigned short* An = &AB_s[1][0][0];
  unsigned short* Bn = &AB_s[1][1][0];

  STAGE(Ac, Bc, 0);
  __syncthreads();

  for (int kt = 0; kt < NT; ++kt) {
    if (kt + 1 < NT) STAGE(An, Bn, kt + 1);
    bf16x8 af[4][2], bfr[4][2];
    #pragma unroll
    for (int i = 0; i < 4; ++i) {
      const int arow = wm * 64 + i * 16 + lm;
      const int brow = wn * 64 + i * 16 + lm;
      #pragma unroll
      for (int ks = 0; ks < 2; ++ks) {
        af[i][ks]  = *(const bf16x8*)&Ac[arow * BK + (((ks * 4 + kg) ^ (arow & 7)) << 3)];
        bfr[i][ks] = *(const bf16x8*)&Bc[brow * BK + (((ks * 4 + kg) ^ (brow & 7)) << 3)];
      }
    }
    #pragma unroll
    for (int ks = 0; ks < 2; ++ks)
      #pragma unroll
      for (int i = 0; i < 4; ++i)
        #pragma unroll
        for (int j = 0; j < 4; ++j)
          acc[i][j] = __builtin_amdgcn_mfma_f32_16x16x32_bf16(af[i][ks], bfr[j][ks], acc[i][j], 0, 0, 0);
    __syncthreads();
    unsigned short* tp;
    tp = Ac; Ac = An; An = tp;
    tp = Bc; Bc = Bn; Bn = tp;
  }

  #pragma unroll
  for (int i = 0; i < 4; ++i) {
    #pragma unroll
    for (int rr = 0; rr < 4; ++rr) {
      const int mloc = wm * 64 + i * 16 + kg * 4 + rr;
      const float s0 = st_s[mloc][0], s1 = st_s[mloc][1], s2 = st_s[mloc][2];
      float* orow = out + (size_t)(m0 + mloc) * V_ + n0;
      #pragma unroll
      for (int j = 0; j < 4; ++j) {
        const int nloc = wn * 64 + j * 16 + lm;
        if (n0 + nloc < V_) {
          const float corr = 0.1f * (s0 * wm_s[nloc][0] + s1 * wm_s[nloc][1] + s2 * wm_s[nloc][2]);
          orow[nloc] = acc[i][j][rr] + corr;
        }
      }
    }
  }
}

// ---------------- Last-resort (tiny ws): f32 reg-staged GEMM (R1)
__global__ __launch_bounds__(256) void ttu_gemm_kernel(
    const float* __restrict__ Ag, const float* __restrict__ Bg,
    const float* __restrict__ states, const float* __restrict__ Wmod,
    float* __restrict__ out)
{
  __shared__ unsigned short A_s[128][40];
  __shared__ unsigned short B_s[128][40];
  __shared__ float st_s[128][3];
  __shared__ float wm_s[128][3];

  const int t   = threadIdx.x;
  const int bid = blockIdx.x;
  const int mb  = bid & 15;
  const int nb  = bid >> 4;
  const int m0  = mb * 128;
  const int n0  = nb * 128;

  if (t < 128) {
    const int m = m0 + t;
    const int b = m >> 10;
    const int s = m & (S_ - 1);
    const float* st = states + (size_t)(s * B_ + b) * 3;
    st_s[t][0] = st[0]; st_s[t][1] = st[1]; st_s[t][2] = st[2];
  } else {
    const int tt = t - 128;
    const int n  = n0 + tt;
    const bool ok = n < V_;
    wm_s[tt][0] = ok ? Wmod[n * 3 + 0] : 0.f;
    wm_s[tt][1] = ok ? Wmod[n * 3 + 1] : 0.f;
    wm_s[tt][2] = ok ? Wmod[n * 3 + 2] : 0.f;
  }

  const int r   = t >> 1;
  const int seg = t & 1;
  const float* arow = Ag + (size_t)(m0 + r) * H_ + seg * 16;
  const int  vrow = n0 + r;
  const bool bok  = vrow < V_;
  const float* brow = Bg + (size_t)(bok ? vrow : 0) * H_ + seg * 16;

  const int lane = t & 63;
  const int wid  = t >> 6;
  const int wm   = wid >> 1;
  const int wn   = wid & 1;
  const int lm   = lane & 15;
  const int kg   = lane >> 4;

  f32x4 acc[4][4];
  #pragma unroll
  for (int i = 0; i < 4; ++i)
    #pragma unroll
    for (int j = 0; j < 4; ++j)
      acc[i][j] = (f32x4){0.f, 0.f, 0.f, 0.f};

  for (int kt = 0; kt < H_ / 32; ++kt) {
    const int k0 = kt * 32;
    const float4 av0 = *(const float4*)(arow + k0 + 0);
    const float4 av1 = *(const float4*)(arow + k0 + 4);
    const float4 av2 = *(const float4*)(arow + k0 + 8);
    const float4 av3 = *(const float4*)(arow + k0 + 12);
    float4 bv0 = {0,0,0,0}, bv1 = {0,0,0,0}, bv2 = {0,0,0,0}, bv3 = {0,0,0,0};
    if (bok) {
      bv0 = *(const float4*)(brow + k0 + 0);
      bv1 = *(const float4*)(brow + k0 + 4);
      bv2 = *(const float4*)(brow + k0 + 8);
      bv3 = *(const float4*)(brow + k0 + 12);
    }
    __syncthreads();
    #define CVT4(v) (bf16x4){(short)f2bf((v).x), (short)f2bf((v).y), (short)f2bf((v).z), (short)f2bf((v).w)}
    *(bf16x4*)&A_s[r][seg * 16 + 0]  = CVT4(av0);
    *(bf16x4*)&A_s[r][seg * 16 + 4]  = CVT4(av1);
    *(bf16x4*)&A_s[r][seg * 16 + 8]  = CVT4(av2);
    *(bf16x4*)&A_s[r][seg * 16 + 12] = CVT4(av3);
    *(bf16x4*)&B_s[r][seg * 16 + 0]  = CVT4(bv0);
    *(bf16x4*)&B_s[r][seg * 16 + 4]  = CVT4(bv1);
    *(bf16x4*)&B_s[r][seg * 16 + 8]  = CVT4(bv2);
    *(bf16x4*)&B_s[r][seg * 16 + 12] = CVT4(bv3);
    #undef CVT4
    __syncthreads();
    bf16x8 af[4], bf[4];
    #pragma unroll
    for (int i = 0; i < 4; ++i) {
      af[i] = *(const bf16x8*)&A_s[wm * 64 + i * 16 + lm][kg * 8];
      bf[i] = *(const bf16x8*)&B_s[wn * 64 + i * 16 + lm][kg * 8];
    }
    #pragma unroll
    for (int i = 0; i < 4; ++i)
      #pragma unroll
      for (int j = 0; j < 4; ++j)
        acc[i][j] = __builtin_amdgcn_mfma_f32_16x16x32_bf16(af[i], bf[j], acc[i][j], 0, 0, 0);
  }

  #pragma unroll
  for (int i = 0; i < 4; ++i) {
    #pragma unroll
    for (int rr = 0; rr < 4; ++rr) {
      const int mloc = wm * 64 + i * 16 + kg * 4 + rr;
      const float s0 = st_s[mloc][0], s1 = st_s[mloc][1], s2 = st_s[mloc][2];
      float* orow = out + (size_t)(m0 + mloc) * V_ + n0;
      #pragma unroll
      for (int j = 0; j < 4; ++j) {
        const int nloc = wn * 64 + j * 16 + lm;
        if (n0 + nloc < V_) {
          const float corr = 0.1f * (s0 * wm_s[nloc][0] + s1 * wm_s[nloc][1] + s2 * wm_s[nloc][2]);
          orow[nloc] = acc[i][j][rr] + corr;
        }
      }
    }
  }
}

} // namespace

extern "C" void kernel_launch(void* const* d_in, const int* in_sizes, int n_in,
                              void* d_out, int out_size, void* d_ws, size_t ws_size,
                              hipStream_t stream) {
  const float* hidden     = (const float*)d_in[0];
  const float* ttu_state  = (const float*)d_in[1];
  const float* W_imp      = (const float*)d_in[2];
  const float* b_imp      = (const float*)d_in[3];
  const float* W_lm       = (const float*)d_in[4];
  const float* W_mod      = (const float*)d_in[5];
  const float* ttu_params = (const float*)d_in[6];
  float* out = (float*)d_out;

  float* imp    = (float*)d_ws;          // 2048 f32
  float* states = imp + S_ * B_;         // 6144 f32  (32 KB total)
  float* final_out = out + (size_t)B_ * S_ * V_;

  const size_t need256 = 32768 + (size_t)M_ * H_ * 2 + (size_t)VP2_ * H_ * 2;
  const size_t need128 = 32768 + (size_t)M_ * H_ * 2 + (size_t)VP1_ * H_ * 2;

  if (ws_size >= need256) {
    unsigned short* hid_bf = (unsigned short*)((char*)d_ws + 32768);
    unsigned short* wlm_bf = hid_bf + (size_t)M_ * H_;
    cvt_hidden_impulse_kernel<<<M_, 256, 0, stream>>>(hidden, W_imp, b_imp, hid_bf, imp);
    cvt_wlm_scan_kernel<<<4097, 256, 0, stream>>>(W_lm, wlm_bf,
                                                  (long)V_ * H_, (long)VP2_ * H_,
                                                  imp, ttu_state, ttu_params,
                                                  states, final_out);
    const int grid = (VP2_ / 256) * (M_ / 256);   // 197*8 = 1576
    ttu_gemm_bf16_256_kernel<<<grid, 512, 0, stream>>>(hid_bf, wlm_bf, states, W_mod, out);
  } else if (ws_size >= need128) {
    unsigned short* hid_bf = (unsigned short*)((char*)d_ws + 32768);
    unsigned short* wlm_bf = hid_bf + (size_t)M_ * H_;
    cvt_hidden_impulse_kernel<<<M_, 256, 0, stream>>>(hidden, W_imp, b_imp, hid_bf, imp);
    ttu_scan_kernel<<<1, 64, 0, stream>>>(imp, ttu_state, ttu_params, states, final_out);
    cvt_bf16_kernel<<<4096, 256, 0, stream>>>(W_lm, wlm_bf, (long)V_ * H_, (long)VP1_ * H_);
    const int grid = (VP1_ / 128) * (M_ / 128);   // 393*16 = 6288
    ttu_gemm_bf16_db_kernel<<<grid, 256, 0, stream>>>(hid_bf, wlm_bf, states, W_mod, out);
  } else {
    cvt_hidden_impulse_kernel<<<M_, 256, 0, stream>>>(hidden, W_imp, b_imp,
                                                      (unsigned short*)d_ws, imp);
    ttu_scan_kernel<<<1, 64, 0, stream>>>(imp, ttu_state, ttu_params, states, final_out);
    const int grid = ((V_ + 127) / 128) * (M_ / 128);
    ttu_gemm_kernel<<<grid, 256, 0, stream>>>(hidden, W_lm, states, W_mod, out);
  }
}

// Round 5
// 483.257 us; speedup vs baseline: 1.1397x; 1.1397x over previous
//
#include <hip/hip_runtime.h>
#include <hip/hip_bf16.h>

typedef float  f32x4  __attribute__((ext_vector_type(4)));
typedef short  bf16x8 __attribute__((ext_vector_type(8)));
typedef short  bf16x4 __attribute__((ext_vector_type(4)));

typedef const void __attribute__((address_space(1))) gv_t;
typedef void __attribute__((address_space(3))) sv_t;

namespace {

constexpr int B_ = 2;
constexpr int S_ = 1024;
constexpr int H_ = 1024;
constexpr int V_ = 50257;
constexpr int M_ = B_ * S_;          // 2048
constexpr int VP2_ = 50432;          // 197*256, zero-padded W_lm rows (fast path)
constexpr int VP1_ = 50304;          // 393*128 (mid path)
constexpr float DT_ = 0.1f;
constexpr float THRESH_ = 10.0f;

constexpr int BK = 64;
constexpr int NT = H_ / BK;          // 16 K-tiles

__device__ __forceinline__ unsigned short f2bf(float f) {
  union { float f; unsigned u; } x;
  x.f = f;
  x.u += 0x7FFFu + ((x.u >> 16) & 1u);   // RNE (no NaNs in this problem)
  return (unsigned short)(x.u >> 16);
}

// ---------------- Kernel 1: hidden f32 -> bf16, fused with impulse dot
__global__ void cvt_hidden_impulse_kernel(const float* __restrict__ hidden,
                                          const float* __restrict__ W_imp,
                                          const float* __restrict__ b_imp,
                                          unsigned short* __restrict__ hid_bf,
                                          float* __restrict__ imp) {
  const int m = blockIdx.x;
  const int t = threadIdx.x;
  const float4 hv = reinterpret_cast<const float4*>(hidden + (size_t)m * H_)[t];
  const float4 wv = reinterpret_cast<const float4*>(W_imp)[t];   // row 0
  bf16x4 o;
  o[0] = (short)f2bf(hv.x); o[1] = (short)f2bf(hv.y);
  o[2] = (short)f2bf(hv.z); o[3] = (short)f2bf(hv.w);
  *(bf16x4*)(hid_bf + (size_t)m * H_ + t * 4) = o;
  float p = hv.x * wv.x + hv.y * wv.y + hv.z * wv.z + hv.w * wv.w;
  #pragma unroll
  for (int off = 32; off; off >>= 1) p += __shfl_down(p, off);
  __shared__ float partial[4];
  if ((t & 63) == 0) partial[t >> 6] = p;
  __syncthreads();
  if (t == 0) {
    const float v = partial[0] + partial[1] + partial[2] + partial[3] + b_imp[0];
    const int b = m >> 10;
    const int s = m & (S_ - 1);
    imp[s * B_ + b] = v;
  }
}

// ---------------- scan body (device fn; used standalone and fused)
__device__ __forceinline__ void scan_body(const float* __restrict__ imp_s,
                                          const float* __restrict__ ttu_state,
                                          const float* __restrict__ ttu_params,
                                          float* __restrict__ states,
                                          float* __restrict__ final_out, int t) {
  if (t < B_) {
    const float gamma   = ttu_params[0];
    const float alpha_c = ttu_params[1];
    const float beta_c  = ttu_params[2];
    const float delta   = ttu_params[3];
    const float alpha_d = ttu_params[4];
    const float epsilon = ttu_params[5];
    const float alpha_m = ttu_params[6];
    float c = ttu_state[t * 3 + 0];
    float d = ttu_state[t * 3 + 1];
    float m = ttu_state[t * 3 + 2];
    for (int s = 0; s < S_; ++s) {
      const float ii = imp_s[s * B_ + t];
      const float dc = gamma * ii - alpha_c * c - beta_c * c * d;
      const float dd = delta * c * c - alpha_d * d;
      const float dm = epsilon * d - alpha_m * m;
      c = c + DT_ * dc;
      float nd = d + DT_ * dd;
      m = m + DT_ * dm;
      nd = (fabsf(nd) > THRESH_ ? 0.5f : 1.0f) * nd;
      d = nd;
      float* st = states + (size_t)(s * B_ + t) * 3;
      st[0] = c; st[1] = d; st[2] = m;
    }
    final_out[t * 3 + 0] = c;
    final_out[t * 3 + 1] = d;
    final_out[t * 3 + 2] = m;
  }
}

// ---------------- Kernel 2 (standalone scan, fallback paths)
__global__ void ttu_scan_kernel(const float* __restrict__ imp,
                                const float* __restrict__ ttu_state,
                                const float* __restrict__ ttu_params,
                                float* __restrict__ states,
                                float* __restrict__ final_out) {
  __shared__ float imp_s[S_ * B_];
  const int t = threadIdx.x;  // 64
  for (int i = t; i < S_ * B_; i += 64) imp_s[i] = imp[i];
  __syncthreads();
  scan_body(imp_s, ttu_state, ttu_params, states, final_out, t);
}

// ---------------- Kernel 2.5: W_lm f32 -> bf16 (zero-fill pad rows), scan fused
__global__ void cvt_wlm_scan_kernel(const float* __restrict__ src,
                                    unsigned short* __restrict__ dst,
                                    long n_src, long n_dst,
                                    const float* __restrict__ imp,
                                    const float* __restrict__ ttu_state,
                                    const float* __restrict__ ttu_params,
                                    float* __restrict__ states,
                                    float* __restrict__ final_out) {
  __shared__ float imp_s[S_ * B_];
  const int t = threadIdx.x;   // 256
  if (blockIdx.x == gridDim.x - 1) {
    for (int i = t; i < S_ * B_; i += 256) imp_s[i] = imp[i];
    __syncthreads();
    scan_body(imp_s, ttu_state, ttu_params, states, final_out, t);
    return;
  }
  const long stride = (long)(gridDim.x - 1) * blockDim.x * 8;
  for (long i = ((long)blockIdx.x * blockDim.x + t) * 8; i < n_dst; i += stride) {
    bf16x8 v;
    if (i < n_src) {     // n_src multiple of 8; vectors never straddle
      const float4 a = *(const float4*)(src + i);
      const float4 b = *(const float4*)(src + i + 4);
      v[0] = (short)f2bf(a.x); v[1] = (short)f2bf(a.y);
      v[2] = (short)f2bf(a.z); v[3] = (short)f2bf(a.w);
      v[4] = (short)f2bf(b.x); v[5] = (short)f2bf(b.y);
      v[6] = (short)f2bf(b.z); v[7] = (short)f2bf(b.w);
    } else {
      v = (bf16x8){0, 0, 0, 0, 0, 0, 0, 0};
    }
    *(bf16x8*)(dst + i) = v;
  }
}

__global__ void cvt_bf16_kernel(const float* __restrict__ src,
                                unsigned short* __restrict__ dst,
                                long n_src, long n_dst) {
  const long stride = (long)gridDim.x * blockDim.x * 8;
  for (long i = ((long)blockIdx.x * blockDim.x + threadIdx.x) * 8; i < n_dst; i += stride) {
    bf16x8 v;
    if (i < n_src) {
      const float4 a = *(const float4*)(src + i);
      const float4 b = *(const float4*)(src + i + 4);
      v[0] = (short)f2bf(a.x); v[1] = (short)f2bf(a.y);
      v[2] = (short)f2bf(a.z); v[3] = (short)f2bf(a.w);
      v[4] = (short)f2bf(b.x); v[5] = (short)f2bf(b.y);
      v[6] = (short)f2bf(b.z); v[7] = (short)f2bf(b.w);
    } else {
      v = (bf16x8){0, 0, 0, 0, 0, 0, 0, 0};
    }
    *(bf16x8*)(dst + i) = v;
  }
}

// ---------------- Kernel 3 (fast): 256x256, free-running counted-vmcnt loop
// Per tile kt (race-free ledger, 2 barriers + 1 counted vmcnt, NO other pins):
//   1. s_barrier (memory-clobber): all waves done reading tile kt-1
//      -> WAR-safe to overwrite buf[nxt] (kt-1's buffer) with tile kt+1.
//   2. STAGE_ALL(nxt, kt+1): 8 gload_lds/wave, full-tile prefetch distance.
//   3. s_waitcnt vmcnt(8): per-wave FIFO drain of exactly tile kt's 8 loads
//      (kt+1's 8 remain in flight). Last tile: vmcnt(0).
//   4. s_barrier (memory-clobber): publish -> all waves' kt loads landed.
//   5. Compute 4 quadrants free-running; A-frags of quadrant q+1 load under
//      quadrant q's MFMA burst (compiler-scheduled, no sched_barrier pins).
__global__ __launch_bounds__(512, 2) void ttu_gemm_bf16_256v2_kernel(
    const unsigned short* __restrict__ Ab,   // hidden bf16 [M_][H_]
    const unsigned short* __restrict__ Bb,   // W_lm bf16 [VP2_][H_]
    const float* __restrict__ states,
    const float* __restrict__ Wmod,
    float* __restrict__ out)
{
  __shared__ unsigned short A_s[2][256 * BK];   // 64 KiB
  __shared__ unsigned short B_s[2][256 * BK];   // 64 KiB
  __shared__ float st_s[256][3];
  __shared__ float wm_s[256][3];

  const int t = threadIdx.x;
  const int cpx = gridDim.x >> 3;              // 197; grid 1576 % 8 == 0
  const int bid = (blockIdx.x & 7) * cpx + (blockIdx.x >> 3);
  const int mb = bid & 7;                      // M fastest: share B-panel
  const int nb = bid >> 3;
  const int m0 = mb * 256;
  const int n0 = nb * 256;

  if (t < 256) {
    const int m = m0 + t;
    const int b = m >> 10;
    const int s = m & (S_ - 1);
    const float* st = states + (size_t)(s * B_ + b) * 3;
    st_s[t][0] = st[0]; st_s[t][1] = st[1]; st_s[t][2] = st[2];
  } else {
    const int tt = t - 256;
    const int n = n0 + tt;
    const bool ok = n < V_;
    wm_s[tt][0] = ok ? Wmod[n * 3 + 0] : 0.f;
    wm_s[tt][1] = ok ? Wmod[n * 3 + 1] : 0.f;
    wm_s[tt][2] = ok ? Wmod[n * 3 + 2] : 0.f;
  }

  const int lane = t & 63;
  const int wid  = t >> 6;             // 8 waves
  const int lr   = lane >> 3;          // staging sub-row 0..7
  const int ch   = lane & 7;           // staging 16B chunk 0..7
  const int wmi  = wid >> 2;           // wave row 0..1 (128 rows each)
  const int wni  = wid & 3;            // wave col 0..3 (64 cols each)
  const int lm   = lane & 15;
  const int kg   = lane >> 4;

  const unsigned short* Abase = Ab + (size_t)m0 * H_;
  const unsigned short* Bbase = Bb + (size_t)n0 * H_;

  // stage all 4 halves (A rows 0-127, A 128-255, B 0-127, B 128-255) of tile
  // kt into buf: 8 gload_lds per wave. LDS dest = wave-uniform base +
  // lane*16B (linear, rule #21); SOURCE chunk pre-swizzled: LDS[r][c] =
  // G[r][c ^ (r&7)]; ds_read applies the same XOR. (Verified passing R2-R4.)
  auto STAGE_ALL = [&](int buf, int kt) {
    const int k0 = kt * BK;
    #pragma unroll
    for (int h = 0; h < 4; ++h) {
      const unsigned short* gb = (h < 2) ? Abase : Bbase;
      unsigned short* ls = (h < 2) ? &A_s[buf][0] : &B_s[buf][0];
      const int half = (h & 1) * 128;
      #pragma unroll
      for (int n = 0; n < 2; ++n) {
        const int rbase = half + wid * 16 + n * 8;   // wave-uniform
        const int r  = rbase + lr;
        const int sc = ch ^ (r & 7);
        __builtin_amdgcn_global_load_lds(
            (gv_t*)(gb + (size_t)r * H_ + k0 + sc * 8),
            (sv_t*)(ls + rbase * BK), 16, 0, 0);
      }
    }
  };

  f32x4 acc[8][4];
  #pragma unroll
  for (int i = 0; i < 8; ++i)
    #pragma unroll
    for (int j = 0; j < 4; ++j)
      acc[i][j] = (f32x4){0.f, 0.f, 0.f, 0.f};

  // prologue: issue tile 0's loads; the loop's first vmcnt/barrier drains them
  STAGE_ALL(0, 0);

  int cur = 0;
  for (int kt = 0; kt < NT; ++kt) {
    const int nxt = cur ^ 1;
    asm volatile("s_barrier" ::: "memory");        // WAR: prev reads of buf[nxt] done
    if (kt + 1 < NT) {
      STAGE_ALL(nxt, kt + 1);
      asm volatile("s_waitcnt vmcnt(8)" ::: "memory");   // drain tile kt's 8
    } else {
      asm volatile("s_waitcnt vmcnt(0)" ::: "memory");
    }
    asm volatile("s_barrier" ::: "memory");        // publish tile kt

    const unsigned short* As = &A_s[cur][0];
    const unsigned short* Bs = &B_s[cur][0];

    bf16x8 bfr[4][2];
    #pragma unroll
    for (int j = 0; j < 4; ++j)
      #pragma unroll
      for (int ks = 0; ks < 2; ++ks) {
        const int r = wni * 64 + j * 16 + lm;
        bfr[j][ks] = *(const bf16x8*)&Bs[r * BK + (((ks * 4 + kg) ^ (r & 7)) << 3)];
      }
    bf16x8 af[2][2][2];   // [ping][i2][ks] — all indices static after unroll
    #pragma unroll
    for (int i2 = 0; i2 < 2; ++i2)
      #pragma unroll
      for (int ks = 0; ks < 2; ++ks) {
        const int r = wmi * 128 + i2 * 16 + lm;
        af[0][i2][ks] = *(const bf16x8*)&As[r * BK + (((ks * 4 + kg) ^ (r & 7)) << 3)];
      }
    #pragma unroll
    for (int q = 0; q < 4; ++q) {
      if (q < 3) {      // next quadrant's A-frags load under this MFMA burst
        #pragma unroll
        for (int i2 = 0; i2 < 2; ++i2)
          #pragma unroll
          for (int ks = 0; ks < 2; ++ks) {
            const int r = wmi * 128 + ((q + 1) * 2 + i2) * 16 + lm;
            af[(q + 1) & 1][i2][ks] =
                *(const bf16x8*)&As[r * BK + (((ks * 4 + kg) ^ (r & 7)) << 3)];
          }
      }
      __builtin_amdgcn_s_setprio(1);
      #pragma unroll
      for (int ks = 0; ks < 2; ++ks)
        #pragma unroll
        for (int i2 = 0; i2 < 2; ++i2)
          #pragma unroll
          for (int j = 0; j < 4; ++j)
            acc[q * 2 + i2][j] = __builtin_amdgcn_mfma_f32_16x16x32_bf16(
                af[q & 1][i2][ks], bfr[j][ks], acc[q * 2 + i2][j], 0, 0, 0);
      __builtin_amdgcn_s_setprio(0);
    }
    cur ^= 1;
  }

  // Epilogue: += 0.1 * states . W_mod^T; row-major store order
  #pragma unroll
  for (int i = 0; i < 8; ++i) {
    #pragma unroll
    for (int rr = 0; rr < 4; ++rr) {
      const int mloc = wmi * 128 + i * 16 + kg * 4 + rr;
      const float s0 = st_s[mloc][0], s1 = st_s[mloc][1], s2 = st_s[mloc][2];
      float* orow = out + (size_t)(m0 + mloc) * V_ + n0;
      #pragma unroll
      for (int j = 0; j < 4; ++j) {
        const int nloc = wni * 64 + j * 16 + lm;
        if (n0 + nloc < V_) {
          const float corr = 0.1f * (s0 * wm_s[nloc][0] + s1 * wm_s[nloc][1] + s2 * wm_s[nloc][2]);
          orow[nloc] = acc[i][j][rr] + corr;
        }
      }
    }
  }
}

// ---------------- Kernel 3 (mid fallback): R3 128x128 2-phase double-buffer
__global__ __launch_bounds__(256) void ttu_gemm_bf16_db_kernel(
    const unsigned short* __restrict__ Ab,
    const unsigned short* __restrict__ Bb,   // [VP1_][H_]
    const float* __restrict__ states,
    const float* __restrict__ Wmod,
    float* __restrict__ out)
{
  __shared__ unsigned short AB_s[2][2][128 * BK];
  __shared__ float st_s[128][3];
  __shared__ float wm_s[128][3];

  const int t = threadIdx.x;
  const int cpx = gridDim.x >> 3;
  const int bid = (blockIdx.x & 7) * cpx + (blockIdx.x >> 3);
  const int mb = bid & 15;
  const int nb = bid >> 4;
  const int m0 = mb * 128;
  const int n0 = nb * 128;

  if (t < 128) {
    const int m = m0 + t;
    const int b = m >> 10;
    const int s = m & (S_ - 1);
    const float* st = states + (size_t)(s * B_ + b) * 3;
    st_s[t][0] = st[0]; st_s[t][1] = st[1]; st_s[t][2] = st[2];
  } else {
    const int tt = t - 128;
    const int n = n0 + tt;
    const bool ok = n < V_;
    wm_s[tt][0] = ok ? Wmod[n * 3 + 0] : 0.f;
    wm_s[tt][1] = ok ? Wmod[n * 3 + 1] : 0.f;
    wm_s[tt][2] = ok ? Wmod[n * 3 + 2] : 0.f;
  }

  const int lane = t & 63;
  const int wid  = t >> 6;
  const int lr   = lane >> 3;
  const int ch   = lane & 7;
  const int wm   = wid >> 1;
  const int wn   = wid & 1;
  const int lm   = lane & 15;
  const int kg   = lane >> 4;

  const unsigned short* Abase = Ab + (size_t)m0 * H_;
  const unsigned short* Bbase = Bb + (size_t)n0 * H_;
  const int r0 = wid * 32;

  auto STAGE = [&](unsigned short* As, unsigned short* Bs, int kt) {
    const int k0 = kt * BK;
    #pragma unroll
    for (int ins = 0; ins < 4; ++ins) {
      const int lrow = r0 + ins * 8 + lr;
      const int sch  = ch ^ (lrow & 7);
      __builtin_amdgcn_global_load_lds(
          (gv_t*)(Abase + (size_t)lrow * H_ + k0 + sch * 8),
          (sv_t*)(As + (r0 + ins * 8) * BK), 16, 0, 0);
    }
    #pragma unroll
    for (int ins = 0; ins < 4; ++ins) {
      const int lrow = r0 + ins * 8 + lr;
      const int sch  = ch ^ (lrow & 7);
      __builtin_amdgcn_global_load_lds(
          (gv_t*)(Bbase + (size_t)lrow * H_ + k0 + sch * 8),
          (sv_t*)(Bs + (r0 + ins * 8) * BK), 16, 0, 0);
    }
  };

  f32x4 acc[4][4];
  #pragma unroll
  for (int i = 0; i < 4; ++i)
    #pragma unroll
    for (int j = 0; j < 4; ++j)
      acc[i][j] = (f32x4){0.f, 0.f, 0.f, 0.f};

  unsigned short* Ac = &AB_s[0][0][0];
  unsigned short* Bc = &AB_s[0][1][0];
  unsigned short* An = &AB_s[1][0][0];
  unsigned short* Bn = &AB_s[1][1][0];

  STAGE(Ac, Bc, 0);
  __syncthreads();

  for (int kt = 0; kt < NT; ++kt) {
    if (kt + 1 < NT) STAGE(An, Bn, kt + 1);
    bf16x8 af[4][2], bfr[4][2];
    #pragma unroll
    for (int i = 0; i < 4; ++i) {
      const int arow = wm * 64 + i * 16 + lm;
      const int brow = wn * 64 + i * 16 + lm;
      #pragma unroll
      for (int ks = 0; ks < 2; ++ks) {
        af[i][ks]  = *(const bf16x8*)&Ac[arow * BK + (((ks * 4 + kg) ^ (arow & 7)) << 3)];
        bfr[i][ks] = *(const bf16x8*)&Bc[brow * BK + (((ks * 4 + kg) ^ (brow & 7)) << 3)];
      }
    }
    #pragma unroll
    for (int ks = 0; ks < 2; ++ks)
      #pragma unroll
      for (int i = 0; i < 4; ++i)
        #pragma unroll
        for (int j = 0; j < 4; ++j)
          acc[i][j] = __builtin_amdgcn_mfma_f32_16x16x32_bf16(af[i][ks], bfr[j][ks], acc[i][j], 0, 0, 0);
    __syncthreads();
    unsigned short* tp;
    tp = Ac; Ac = An; An = tp;
    tp = Bc; Bc = Bn; Bn = tp;
  }

  #pragma unroll
  for (int i = 0; i < 4; ++i) {
    #pragma unroll
    for (int rr = 0; rr < 4; ++rr) {
      const int mloc = wm * 64 + i * 16 + kg * 4 + rr;
      const float s0 = st_s[mloc][0], s1 = st_s[mloc][1], s2 = st_s[mloc][2];
      float* orow = out + (size_t)(m0 + mloc) * V_ + n0;
      #pragma unroll
      for (int j = 0; j < 4; ++j) {
        const int nloc = wn * 64 + j * 16 + lm;
        if (n0 + nloc < V_) {
          const float corr = 0.1f * (s0 * wm_s[nloc][0] + s1 * wm_s[nloc][1] + s2 * wm_s[nloc][2]);
          orow[nloc] = acc[i][j][rr] + corr;
        }
      }
    }
  }
}

// ---------------- Last-resort (tiny ws): f32 reg-staged GEMM (R1)
__global__ __launch_bounds__(256) void ttu_gemm_kernel(
    const float* __restrict__ Ag, const float* __restrict__ Bg,
    const float* __restrict__ states, const float* __restrict__ Wmod,
    float* __restrict__ out)
{
  __shared__ unsigned short A_s[128][40];
  __shared__ unsigned short B_s[128][40];
  __shared__ float st_s[128][3];
  __shared__ float wm_s[128][3];

  const int t   = threadIdx.x;
  const int bid = blockIdx.x;
  const int mb  = bid & 15;
  const int nb  = bid >> 4;
  const int m0  = mb * 128;
  const int n0  = nb * 128;

  if (t < 128) {
    const int m = m0 + t;
    const int b = m >> 10;
    const int s = m & (S_ - 1);
    const float* st = states + (size_t)(s * B_ + b) * 3;
    st_s[t][0] = st[0]; st_s[t][1] = st[1]; st_s[t][2] = st[2];
  } else {
    const int tt = t - 128;
    const int n  = n0 + tt;
    const bool ok = n < V_;
    wm_s[tt][0] = ok ? Wmod[n * 3 + 0] : 0.f;
    wm_s[tt][1] = ok ? Wmod[n * 3 + 1] : 0.f;
    wm_s[tt][2] = ok ? Wmod[n * 3 + 2] : 0.f;
  }

  const int r   = t >> 1;
  const int seg = t & 1;
  const float* arow = Ag + (size_t)(m0 + r) * H_ + seg * 16;
  const int  vrow = n0 + r;
  const bool bok  = vrow < V_;
  const float* brow = Bg + (size_t)(bok ? vrow : 0) * H_ + seg * 16;

  const int lane = t & 63;
  const int wid  = t >> 6;
  const int wm   = wid >> 1;
  const int wn   = wid & 1;
  const int lm   = lane & 15;
  const int kg   = lane >> 4;

  f32x4 acc[4][4];
  #pragma unroll
  for (int i = 0; i < 4; ++i)
    #pragma unroll
    for (int j = 0; j < 4; ++j)
      acc[i][j] = (f32x4){0.f, 0.f, 0.f, 0.f};

  for (int kt = 0; kt < H_ / 32; ++kt) {
    const int k0 = kt * 32;
    const float4 av0 = *(const float4*)(arow + k0 + 0);
    const float4 av1 = *(const float4*)(arow + k0 + 4);
    const float4 av2 = *(const float4*)(arow + k0 + 8);
    const float4 av3 = *(const float4*)(arow + k0 + 12);
    float4 bv0 = {0,0,0,0}, bv1 = {0,0,0,0}, bv2 = {0,0,0,0}, bv3 = {0,0,0,0};
    if (bok) {
      bv0 = *(const float4*)(brow + k0 + 0);
      bv1 = *(const float4*)(brow + k0 + 4);
      bv2 = *(const float4*)(brow + k0 + 8);
      bv3 = *(const float4*)(brow + k0 + 12);
    }
    __syncthreads();
    #define CVT4(v) (bf16x4){(short)f2bf((v).x), (short)f2bf((v).y), (short)f2bf((v).z), (short)f2bf((v).w)}
    *(bf16x4*)&A_s[r][seg * 16 + 0]  = CVT4(av0);
    *(bf16x4*)&A_s[r][seg * 16 + 4]  = CVT4(av1);
    *(bf16x4*)&A_s[r][seg * 16 + 8]  = CVT4(av2);
    *(bf16x4*)&A_s[r][seg * 16 + 12] = CVT4(av3);
    *(bf16x4*)&B_s[r][seg * 16 + 0]  = CVT4(bv0);
    *(bf16x4*)&B_s[r][seg * 16 + 4]  = CVT4(bv1);
    *(bf16x4*)&B_s[r][seg * 16 + 8]  = CVT4(bv2);
    *(bf16x4*)&B_s[r][seg * 16 + 12] = CVT4(bv3);
    #undef CVT4
    __syncthreads();
    bf16x8 af[4], bf[4];
    #pragma unroll
    for (int i = 0; i < 4; ++i) {
      af[i] = *(const bf16x8*)&A_s[wm * 64 + i * 16 + lm][kg * 8];
      bf[i] = *(const bf16x8*)&B_s[wn * 64 + i * 16 + lm][kg * 8];
    }
    #pragma unroll
    for (int i = 0; i < 4; ++i)
      #pragma unroll
      for (int j = 0; j < 4; ++j)
        acc[i][j] = __builtin_amdgcn_mfma_f32_16x16x32_bf16(af[i], bf[j], acc[i][j], 0, 0, 0);
  }

  #pragma unroll
  for (int i = 0; i < 4; ++i) {
    #pragma unroll
    for (int rr = 0; rr < 4; ++rr) {
      const int mloc = wm * 64 + i * 16 + kg * 4 + rr;
      const float s0 = st_s[mloc][0], s1 = st_s[mloc][1], s2 = st_s[mloc][2];
      float* orow = out + (size_t)(m0 + mloc) * V_ + n0;
      #pragma unroll
      for (int j = 0; j < 4; ++j) {
        const int nloc = wn * 64 + j * 16 + lm;
        if (n0 + nloc < V_) {
          const float corr = 0.1f * (s0 * wm_s[nloc][0] + s1 * wm_s[nloc][1] + s2 * wm_s[nloc][2]);
          orow[nloc] = acc[i][j][rr] + corr;
        }
      }
    }
  }
}

} // namespace

extern "C" void kernel_launch(void* const* d_in, const int* in_sizes, int n_in,
                              void* d_out, int out_size, void* d_ws, size_t ws_size,
                              hipStream_t stream) {
  const float* hidden     = (const float*)d_in[0];
  const float* ttu_state  = (const float*)d_in[1];
  const float* W_imp      = (const float*)d_in[2];
  const float* b_imp      = (const float*)d_in[3];
  const float* W_lm       = (const float*)d_in[4];
  const float* W_mod      = (const float*)d_in[5];
  const float* ttu_params = (const float*)d_in[6];
  float* out = (float*)d_out;

  float* imp    = (float*)d_ws;          // 2048 f32
  float* states = imp + S_ * B_;         // 6144 f32  (32 KB total)
  float* final_out = out + (size_t)B_ * S_ * V_;

  const size_t need256 = 32768 + (size_t)M_ * H_ * 2 + (size_t)VP2_ * H_ * 2;
  const size_t need128 = 32768 + (size_t)M_ * H_ * 2 + (size_t)VP1_ * H_ * 2;

  if (ws_size >= need256) {
    unsigned short* hid_bf = (unsigned short*)((char*)d_ws + 32768);
    unsigned short* wlm_bf = hid_bf + (size_t)M_ * H_;
    cvt_hidden_impulse_kernel<<<M_, 256, 0, stream>>>(hidden, W_imp, b_imp, hid_bf, imp);
    cvt_wlm_scan_kernel<<<4097, 256, 0, stream>>>(W_lm, wlm_bf,
                                                  (long)V_ * H_, (long)VP2_ * H_,
                                                  imp, ttu_state, ttu_params,
                                                  states, final_out);
    const int grid = (VP2_ / 256) * (M_ / 256);   // 197*8 = 1576
    ttu_gemm_bf16_256v2_kernel<<<grid, 512, 0, stream>>>(hid_bf, wlm_bf, states, W_mod, out);
  } else if (ws_size >= need128) {
    unsigned short* hid_bf = (unsigned short*)((char*)d_ws + 32768);
    unsigned short* wlm_bf = hid_bf + (size_t)M_ * H_;
    cvt_hidden_impulse_kernel<<<M_, 256, 0, stream>>>(hidden, W_imp, b_imp, hid_bf, imp);
    ttu_scan_kernel<<<1, 64, 0, stream>>>(imp, ttu_state, ttu_params, states, final_out);
    cvt_bf16_kernel<<<4096, 256, 0, stream>>>(W_lm, wlm_bf, (long)V_ * H_, (long)VP1_ * H_);
    const int grid = (VP1_ / 128) * (M_ / 128);   // 393*16 = 6288
    ttu_gemm_bf16_db_kernel<<<grid, 256, 0, stream>>>(hid_bf, wlm_bf, states, W_mod, out);
  } else {
    cvt_hidden_impulse_kernel<<<M_, 256, 0, stream>>>(hidden, W_imp, b_imp,
                                                      (unsigned short*)d_ws, imp);
    ttu_scan_kernel<<<1, 64, 0, stream>>>(imp, ttu_state, ttu_params, states, final_out);
    const int grid = ((V_ + 127) / 128) * (M_ / 128);
    ttu_gemm_kernel<<<grid, 256, 0, stream>>>(hidden, W_lm, states, W_mod, out);
  }
}